// Round 9
// baseline (174.990 us; speedup 1.0000x reference)
//
#include <hip/hip_runtime.h>
#include <math.h>

#define T 32
#define K 2048
#define NBLOCKS 256
#define NTHREADS 512
#define CPB 8                           // columns per block (1 per wave)
#define QS 4                            // K / NTHREADS slots per thread (final block)
#define L2E_F 1.4426950408889634f       // log2(e)
#define LN2_F 0.6931471805599453f
#define LOG2PI_F 1.8378770664093453f
#define LOG_K_F  7.6246189861593985f    // ln(2048)
#define SP_F     0.17677669529663687f   // sqrt(1/32)
#define LOG_SP_F (-1.7328679513998633f) // ln(sqrt(1/32))

#if __has_builtin(__builtin_amdgcn_exp2f)
#define EXP2F(x) __builtin_amdgcn_exp2f(x)
#else
#define EXP2F(x) exp2f(x)
#endif
#if __has_builtin(__builtin_amdgcn_logf)
#define LOG2F(x) __builtin_amdgcn_logf(x)
#else
#define LOG2F(x) log2f(x)
#endif

// ALL global sync traffic is relaxed agent-scope atomics: write-through to
// the MALL, bypassing the non-coherent per-XCD L2s. NO release/acquire at
// agent scope anywhere (R2/R7: agent-release costs ~15us/step in L2 cache
// maintenance). Producer ordering (data before sentinel) comes from
// __syncthreads' per-wave vmcnt drain before s_barrier.
__device__ __forceinline__ float aload4(const float* p) {
    return __hip_atomic_load(p, __ATOMIC_RELAXED, __HIP_MEMORY_SCOPE_AGENT);
}
__device__ __forceinline__ void astore4(float* p, float v) {
    __hip_atomic_store(p, v, __ATOMIC_RELAXED, __HIP_MEMORY_SCOPE_AGENT);
}
__device__ __forceinline__ int sload(const int* p) {
    return __hip_atomic_load(p, __ATOMIC_RELAXED, __HIP_MEMORY_SCOPE_AGENT);
}
__device__ __forceinline__ void sstore(int* p, int v) {
    __hip_atomic_store(p, v, __ATOMIC_RELAXED, __HIP_MEMORY_SCOPE_AGENT);
}

// Fully fused dataflow chain, packed-sentinel-gated one-shot reads.
// 256 blocks x 512 threads; block b owns columns [8b, 8b+8), one per wave.
// Sentinels: 256 ints PACKED into 1KB (8 MALL lines) — one poll sweep is 4
// coalesced 64-lane dword loads (vs R8's 256 separate lines = 8MB/sweep).
// Per step: wave 0 precomputes the z-row from eps, polls the packed
// sentinels (signed 1..32; 0xAA poison is negative -> never satisfies >=),
// bulk-reads the 2048-float rho-row EXACTLY ONCE, stages (z, R2) pairs to
// LDS; waves 1-7 wait at the stage barrier. Ping-pong safety: advancing to
// step s+2 requires observing ALL sentinels >= s+1, which requires every
// block's s+1 publish (hence its consumption of step s) — a row is never
// overwritten while readable.
__global__ __launch_bounds__(NTHREADS) void fused_kernel(
    const float* __restrict__ means, const float* __restrict__ log_stds,
    const float* __restrict__ eps, float* __restrict__ rbuf,
    int* __restrict__ sent, float* __restrict__ out)
{
    __shared__ float2 shzr[2][K];    // 32 KB: (z_j, R2_j = rho_j - 16*L2E*z_j^2)
    __shared__ float2 lzc[T][CPB];   // own cols: (tz2 = 32*L2E*z', cm2)
    __shared__ float smu[T], sstd[T];
    __shared__ float red[NTHREADS];

    const int tid  = threadIdx.x;
    const int b    = blockIdx.x;
    const int col0 = b * CPB;

    // ---- setup: threads 0..255, thread (t = tid>>3, dcol = tid&7) ----
    if (tid < T * CPB) {
        int t = tid >> 3, dcol = tid & 7;
        float mu = means[t];
        float st = expf(log_stds[t]);
        if (dcol == 0) { smu[t] = mu; sstd[t] = st; }
        float e = eps[t * K + col0 + dcol];
        float z = fmaf(st, e, mu);
        // (z-mu)/st == e exactly: log_q = -0.5 e^2 - ln(st) - 0.5 ln2pi
        float log_q = fmaf(-0.5f * e, e, -logf(st) - 0.5f * LOG2PI_F);
        float ct = -LOG_SP_F - 0.5f * LOG2PI_F - log_q;
        float tz2 = (32.0f * L2E_F) * z;
        float cm2 = fmaf((-16.0f * L2E_F) * z, z, L2E_F * ct) - 11.0f; // log2K=11
        lzc[t][dcol] = make_float2(tz2, cm2);
        if (t == 0) {
            float zz = z / SP_F;
            float r0 = -0.5f * zz * zz - LOG_SP_F - 0.5f * LOG2PI_F - log_q;
            astore4(&rbuf[col0 + dcol], r0 * L2E_F);   // rho_0, parity 0
        }
    }
    __syncthreads();               // drains wave 0's r0 stores (vmcnt) + LDS init
    if (tid == 0) sstore(&sent[b], 1);

    const int lane = tid & 63;
    const int wave = tid >> 6;     // 0..7: column col0 + wave

    for (int s = 0; s < T - 1; ++s) {
        const int par = s & 1;
        const int need = s + 1;

        if (wave == 0) {
            // ---- pre-poll: z-row from eps (cached coalesced loads) ----
            const float mu_s  = smu[s];
            const float std_s = sstd[s];
            const float* erow = eps + s * K;
            float zv[32];
            #pragma unroll
            for (int q = 0; q < 32; ++q)
                zv[q] = fmaf(std_s, erow[lane + (q << 6)], mu_s);

            // ---- poll 256 packed sentinels: 4 coalesced loads/sweep ----
            for (;;) {
                int v0 = sload(&sent[lane]);
                int v1 = sload(&sent[lane + 64]);
                int v2 = sload(&sent[lane + 128]);
                int v3 = sload(&sent[lane + 192]);
                int mn = min(min(v0, v1), min(v2, v3));
                if (__all(mn >= need)) break;
                __builtin_amdgcn_s_sleep(1);
            }

            // ---- one-shot bulk read of rho-row + stage (z, R2) as b64 ----
            const float* rrow = rbuf + par * K;
            float rv[32];
            #pragma unroll
            for (int q = 0; q < 32; ++q)
                rv[q] = aload4(&rrow[lane + (q << 6)]);
            #pragma unroll
            for (int q = 0; q < 32; ++q) {
                float z = zv[q];
                shzr[par][lane + (q << 6)] =
                    make_float2(z, fmaf((-16.0f * L2E_F) * z, z, rv[q]));
            }
        }
        __syncthreads();   // barrier A: stage ready (waves 1-7 slept here)

        // ---- this wave's column: u in regs, max pass then exp2 pass ----
        const float4* shp = (const float4*)&shzr[par][0];
        float2 zc = lzc[s + 1][wave];
        float tz2 = zc.x, cm2 = zc.y;
        float u[32];
        float m = -INFINITY;
        #pragma unroll
        for (int i = 0; i < 16; ++i) {
            float4 f4 = shp[lane + (i << 6)];
            // u_j = rho_j - 16*L2E*(z'-z_j)^2 + 16*L2E*z'^2 = fma(tz2, z_j, R2_j)
            u[2 * i]     = fmaf(tz2, f4.x, f4.y);
            u[2 * i + 1] = fmaf(tz2, f4.z, f4.w);
            m = fmaxf(m, fmaxf(u[2 * i], u[2 * i + 1]));
        }
        #pragma unroll
        for (int off = 32; off >= 1; off >>= 1)
            m = fmaxf(m, __shfl_xor(m, off, 64));
        float ss = 0.0f;
        #pragma unroll
        for (int i = 0; i < 32; ++i) ss += EXP2F(u[i] - m);
        #pragma unroll
        for (int off = 32; off >= 1; off >>= 1)
            ss += __shfl_xor(ss, off, 64);
        if (lane == 0)
            astore4(&rbuf[(par ^ 1) * K + col0 + wave], cm2 + m + LOG2F(ss));

        // barrier B drains every wave's publish (vmcnt before s_barrier);
        // only then the block's sentinel advances (relaxed store).
        __syncthreads();
        if (tid == 0) sstore(&sent[b], s + 2);
    }

    // ---- final logmeanexp over r_31 + likelihood, block 0 only ----
    if (b == 0) {
        for (;;) {   // one-time poll, all waves
            int v0 = sload(&sent[lane]);
            int v1 = sload(&sent[lane + 64]);
            int v2 = sload(&sent[lane + 128]);
            int v3 = sload(&sent[lane + 192]);
            int mn = min(min(v0, v1), min(v2, v3));
            if (__all(mn >= T)) break;
            __builtin_amdgcn_s_sleep(1);
        }
        const float* rrow = rbuf + 1 * K;       // rho_31 lives in parity 1
        const float* erow = eps + (T - 1) * K;
        const float mu_l  = smu[T - 1];
        const float std_l = sstd[T - 1];
        float vals[QS];
        float m = -INFINITY;
        #pragma unroll
        for (int q = 0; q < QS; ++q) {
            int j = tid + q * NTHREADS;
            float r = aload4(&rrow[j]) * LN2_F;  // back to natural log
            float z = fmaf(std_l, erow[j], mu_l);
            float d = 0.5f - z;
            float v = r + fmaf(-0.5f * d, d, -0.5f * LOG2PI_F);
            vals[q] = v;
            m = fmaxf(m, v);
        }
        red[tid] = m; __syncthreads();
        for (int off = NTHREADS / 2; off >= 1; off >>= 1) {
            if (tid < off) red[tid] = fmaxf(red[tid], red[tid + off]);
            __syncthreads();
        }
        m = red[0]; __syncthreads();
        float ssum = 0.0f;
        #pragma unroll
        for (int q = 0; q < QS; ++q) ssum += __expf(vals[q] - m);
        red[tid] = ssum; __syncthreads();
        for (int off = NTHREADS / 2; off >= 1; off >>= 1) {
            if (tid < off) red[tid] += red[tid + off];
            __syncthreads();
        }
        if (tid == 0) out[0] = m + logf(red[0]) - LOG_K_F;
    }
}

extern "C" void kernel_launch(void* const* d_in, const int* in_sizes, int n_in,
                              void* d_out, int out_size, void* d_ws, size_t ws_size,
                              hipStream_t stream) {
    const float* means    = (const float*)d_in[0];
    const float* log_stds = (const float*)d_in[1];
    const float* eps      = (const float*)d_in[2];
    float* out = (float*)d_out;

    float* rbuf = (float*)d_ws;                 // 2*K rho ping-pong (16 KB)
    int*   sent = (int*)(rbuf + 2 * K);         // 256 packed sentinels (1 KB)

    fused_kernel<<<NBLOCKS, NTHREADS, 0, stream>>>(
        means, log_stds, eps, rbuf, sent, out);
}

// Round 10
// 172.599 us; speedup vs baseline: 1.0139x; 1.0139x over previous
//
#include <hip/hip_runtime.h>
#include <math.h>

#define T 32
#define K 2048
#define NBLOCKS 256
#define NTHREADS 512
#define CPB 8                           // columns per block (1 per wave)
#define QS 4                            // K / NTHREADS slots per thread
#define L2E_F 1.4426950408889634f       // log2(e)
#define LN2_F 0.6931471805599453f
#define LOG2PI_F 1.8378770664093453f
#define LOG_K_F  7.6246189861593985f    // ln(2048)
#define SP_F     0.17677669529663687f   // sqrt(1/32)
#define LOG_SP_F (-1.7328679513998633f) // ln(sqrt(1/32))

#if __has_builtin(__builtin_amdgcn_exp2f)
#define EXP2F(x) __builtin_amdgcn_exp2f(x)
#else
#define EXP2F(x) exp2f(x)
#endif
#if __has_builtin(__builtin_amdgcn_logf)
#define LOG2F(x) __builtin_amdgcn_logf(x)
#else
#define LOG2F(x) log2f(x)
#endif

// ALL global sync traffic is relaxed agent-scope atomics: write-through to
// the MALL, bypassing the non-coherent per-XCD L2s. NO release/acquire at
// agent scope anywhere (R2/R7: agent-release costs ~15us/step in L2 cache
// maintenance). Producer ordering (data before sentinel) comes from
// __syncthreads' per-wave vmcnt drain before s_barrier.
__device__ __forceinline__ float aload4(const float* p) {
    return __hip_atomic_load(p, __ATOMIC_RELAXED, __HIP_MEMORY_SCOPE_AGENT);
}
__device__ __forceinline__ void astore4(float* p, float v) {
    __hip_atomic_store(p, v, __ATOMIC_RELAXED, __HIP_MEMORY_SCOPE_AGENT);
}
__device__ __forceinline__ int sload(const int* p) {
    return __hip_atomic_load(p, __ATOMIC_RELAXED, __HIP_MEMORY_SCOPE_AGENT);
}
__device__ __forceinline__ void sstore(int* p, int v) {
    __hip_atomic_store(p, v, __ATOMIC_RELAXED, __HIP_MEMORY_SCOPE_AGENT);
}

// Fully fused dataflow chain: packed sentinels (R9) + parallel one-shot
// staging (R8), no handoff. 256 blocks x 512 threads; block b owns columns
// [8b, 8b+8), one per wave. Sentinels: 256 ints packed into 1KB (8 MALL
// lines); EVERY wave polls all 256 itself (4 coalesced lane-loads/sweep of
// 8 hot read-shared lines) and proceeds independently to its 1/8 of the
// one-shot rho-row read + LDS stage. Signed sentinel values 1..32: the
// negative 0xAA poison never satisfies >=, so no init kernel. Ping-pong
// safety: advancing to step s+2 requires observing ALL sentinels >= s+1,
// which requires every block's s+1 publish, hence its consumption of step
// s — a row is never overwritten while readable.
__global__ __launch_bounds__(NTHREADS) void fused_kernel(
    const float* __restrict__ means, const float* __restrict__ log_stds,
    const float* __restrict__ eps, float* __restrict__ rbuf,
    int* __restrict__ sent, float* __restrict__ out)
{
    __shared__ float2 shzr[2][K];    // 32 KB: (z_j, R2_j = rho_j - 16*L2E*z_j^2)
    __shared__ float2 lzc[T][CPB];   // own cols: (tz2 = 32*L2E*z', cm2)
    __shared__ float smu[T], sstd[T];
    __shared__ float red[NTHREADS];

    const int tid  = threadIdx.x;
    const int b    = blockIdx.x;
    const int col0 = b * CPB;

    // ---- setup: threads 0..255, thread (t = tid>>3, dcol = tid&7) ----
    if (tid < T * CPB) {
        int t = tid >> 3, dcol = tid & 7;
        float mu = means[t];
        float st = expf(log_stds[t]);
        if (dcol == 0) { smu[t] = mu; sstd[t] = st; }
        float e = eps[t * K + col0 + dcol];
        float z = fmaf(st, e, mu);
        // (z-mu)/st == e exactly: log_q = -0.5 e^2 - ln(st) - 0.5 ln2pi
        float log_q = fmaf(-0.5f * e, e, -logf(st) - 0.5f * LOG2PI_F);
        float ct = -LOG_SP_F - 0.5f * LOG2PI_F - log_q;
        float tz2 = (32.0f * L2E_F) * z;
        float cm2 = fmaf((-16.0f * L2E_F) * z, z, L2E_F * ct) - 11.0f; // log2K=11
        lzc[t][dcol] = make_float2(tz2, cm2);
        if (t == 0) {
            float zz = z / SP_F;
            float r0 = -0.5f * zz * zz - LOG_SP_F - 0.5f * LOG2PI_F - log_q;
            astore4(&rbuf[col0 + dcol], r0 * L2E_F);   // rho_0, parity 0
        }
    }
    __syncthreads();               // drains r0 stores (vmcnt) + LDS init
    if (tid == 0) sstore(&sent[b], 1);

    const int lane = tid & 63;
    const int wave = tid >> 6;     // 0..7: column col0 + wave

    for (int s = 0; s < T - 1; ++s) {
        const int par = s & 1;
        const int need = s + 1;
        const float mu_s  = smu[s];
        const float std_s = sstd[s];
        const float* erow = eps + s * K;

        // ---- pre-poll: this thread's 4 z values (r-independent, cached) ----
        float zloc[QS], nz2[QS];
        #pragma unroll
        for (int q = 0; q < QS; ++q) {
            float e = erow[tid + q * NTHREADS];
            float z = fmaf(std_s, e, mu_s);
            zloc[q] = z;
            nz2[q]  = ((-16.0f * L2E_F) * z) * z;
        }

        // ---- every wave polls all 256 packed sentinels (8 hot lines) ----
        for (;;) {
            int v0 = sload(&sent[lane]);
            int v1 = sload(&sent[lane + 64]);
            int v2 = sload(&sent[lane + 128]);
            int v3 = sload(&sent[lane + 192]);
            int mn = min(min(v0, v1), min(v2, v3));
            if (__all(mn >= need)) break;
            __builtin_amdgcn_s_sleep(1);
        }

        // ---- one-shot parallel bulk read of rho-row (sentinel-gated) ----
        const float* rrow = rbuf + par * K;
        float rv[QS];
        #pragma unroll
        for (int q = 0; q < QS; ++q) rv[q] = aload4(&rrow[tid + q * NTHREADS]);

        // ---- stage (z, R2) pairs: b64 writes, conflict-free ----
        #pragma unroll
        for (int q = 0; q < QS; ++q)
            shzr[par][tid + q * NTHREADS] = make_float2(zloc[q], rv[q] + nz2[q]);
        __syncthreads();   // barrier A: stage ready

        // ---- this wave's column: u in regs, max pass then exp2 pass ----
        const float4* shp = (const float4*)&shzr[par][0];
        float2 zc = lzc[s + 1][wave];
        float tz2 = zc.x, cm2 = zc.y;
        float u[32];
        float m = -INFINITY;
        #pragma unroll
        for (int i = 0; i < 16; ++i) {
            float4 f4 = shp[lane + (i << 6)];
            // u_j = rho_j - 16*L2E*(z'-z_j)^2 + 16*L2E*z'^2 = fma(tz2, z_j, R2_j)
            u[2 * i]     = fmaf(tz2, f4.x, f4.y);
            u[2 * i + 1] = fmaf(tz2, f4.z, f4.w);
            m = fmaxf(m, fmaxf(u[2 * i], u[2 * i + 1]));
        }
        #pragma unroll
        for (int off = 32; off >= 1; off >>= 1)
            m = fmaxf(m, __shfl_xor(m, off, 64));
        float ss = 0.0f;
        #pragma unroll
        for (int i = 0; i < 32; ++i) ss += EXP2F(u[i] - m);
        #pragma unroll
        for (int off = 32; off >= 1; off >>= 1)
            ss += __shfl_xor(ss, off, 64);
        if (lane == 0)
            astore4(&rbuf[(par ^ 1) * K + col0 + wave], cm2 + m + LOG2F(ss));

        // barrier B drains every wave's publish (vmcnt before s_barrier);
        // only then the block's sentinel advances (relaxed store).
        __syncthreads();
        if (tid == 0) sstore(&sent[b], s + 2);
    }

    // ---- final logmeanexp over r_31 + likelihood, block 0 only ----
    if (b == 0) {
        for (;;) {   // one-time poll, all waves
            int v0 = sload(&sent[lane]);
            int v1 = sload(&sent[lane + 64]);
            int v2 = sload(&sent[lane + 128]);
            int v3 = sload(&sent[lane + 192]);
            int mn = min(min(v0, v1), min(v2, v3));
            if (__all(mn >= T)) break;
            __builtin_amdgcn_s_sleep(1);
        }
        const float* rrow = rbuf + 1 * K;       // rho_31 lives in parity 1
        const float* erow = eps + (T - 1) * K;
        const float mu_l  = smu[T - 1];
        const float std_l = sstd[T - 1];
        float vals[QS];
        float m = -INFINITY;
        #pragma unroll
        for (int q = 0; q < QS; ++q) {
            int j = tid + q * NTHREADS;
            float r = aload4(&rrow[j]) * LN2_F;  // back to natural log
            float z = fmaf(std_l, erow[j], mu_l);
            float d = 0.5f - z;
            float v = r + fmaf(-0.5f * d, d, -0.5f * LOG2PI_F);
            vals[q] = v;
            m = fmaxf(m, v);
        }
        red[tid] = m; __syncthreads();
        for (int off = NTHREADS / 2; off >= 1; off >>= 1) {
            if (tid < off) red[tid] = fmaxf(red[tid], red[tid + off]);
            __syncthreads();
        }
        m = red[0]; __syncthreads();
        float ssum = 0.0f;
        #pragma unroll
        for (int q = 0; q < QS; ++q) ssum += __expf(vals[q] - m);
        red[tid] = ssum; __syncthreads();
        for (int off = NTHREADS / 2; off >= 1; off >>= 1) {
            if (tid < off) red[tid] += red[tid + off];
            __syncthreads();
        }
        if (tid == 0) out[0] = m + logf(red[0]) - LOG_K_F;
    }
}

extern "C" void kernel_launch(void* const* d_in, const int* in_sizes, int n_in,
                              void* d_out, int out_size, void* d_ws, size_t ws_size,
                              hipStream_t stream) {
    const float* means    = (const float*)d_in[0];
    const float* log_stds = (const float*)d_in[1];
    const float* eps      = (const float*)d_in[2];
    float* out = (float*)d_out;

    float* rbuf = (float*)d_ws;                 // 2*K rho ping-pong (16 KB)
    int*   sent = (int*)(rbuf + 2 * K);         // 256 packed sentinels (1 KB)

    fused_kernel<<<NBLOCKS, NTHREADS, 0, stream>>>(
        means, log_stds, eps, rbuf, sent, out);
}

// Round 11
// 119.850 us; speedup vs baseline: 1.4601x; 1.4401x over previous
//
#include <hip/hip_runtime.h>
#include <math.h>

#define T 32
#define K 2048
#define NBLOCKS 256
#define NTHREADS 512
#define HB 128                          // blocks per direction
#define CPB 16                          // columns per block (2 per wave)
#define QS 4                            // K / NTHREADS slots per thread
#define L2E_F 1.4426950408889634f       // log2(e)
#define LN2_F 0.6931471805599453f
#define LOG2PI_F 1.8378770664093453f
#define LOG_K_F  7.6246189861593985f    // ln(2048)
#define SP_F     0.17677669529663687f   // sqrt(1/32)
#define LOG_SP_F (-1.7328679513998633f) // ln(sqrt(1/32))
#define CNORM_F  (-(LOG_SP_F) - 0.5f * LOG2PI_F)   // -ln(sp) - 0.5 ln2pi

#if __has_builtin(__builtin_amdgcn_exp2f)
#define EXP2F(x) __builtin_amdgcn_exp2f(x)
#else
#define EXP2F(x) exp2f(x)
#endif
#if __has_builtin(__builtin_amdgcn_logf)
#define LOG2F(x) __builtin_amdgcn_logf(x)
#else
#define LOG2F(x) log2f(x)
#endif

// ALL global sync traffic is relaxed agent-scope atomics (write-through to
// the MALL, bypassing non-coherent per-XCD L2s). NO agent-scope
// release/acquire anywhere (R2/R7: ~15us/step of L2 cache maintenance).
// Producer ordering (data before sentinel) = __syncthreads' per-wave vmcnt
// drain before s_barrier.
__device__ __forceinline__ float aload4(const float* p) {
    return __hip_atomic_load(p, __ATOMIC_RELAXED, __HIP_MEMORY_SCOPE_AGENT);
}
__device__ __forceinline__ void astore4(float* p, float v) {
    __hip_atomic_store(p, v, __ATOMIC_RELAXED, __HIP_MEMORY_SCOPE_AGENT);
}
__device__ __forceinline__ int sload(const int* p) {
    return __hip_atomic_load(p, __ATOMIC_RELAXED, __HIP_MEMORY_SCOPE_AGENT);
}
__device__ __forceinline__ void sstore(int* p, int v) {
    __hip_atomic_store(p, v, __ATOMIC_RELAXED, __HIP_MEMORY_SCOPE_AGENT);
}

// Bidirectional meet-in-the-middle chain. Blocks 0..127 run the FORWARD
// row-vector chain (r_1..r_16), blocks 128..255 the BACKWARD column-vector
// chain (c_30..c_16 seeded by the likelihood c_31). out = lse_j(r_16[j] +
// c_16[j]) - lnK. Critical path = 16 steps instead of 31.
// Per direction: R8's proven protocol — 128 sentinels packed in 4 MALL
// lines, ONE polling wave per block (2 lane-loads/sweep; ~128 same-line
// accesses/line/sweep — R10 showed all-wave polling serializes at the
// MALL), LDS-flag handoff (workgroup scope, lgkmcnt-only), then parallel
// one-shot staged read of the 2048-float message row. Signed sentinels
// 1..17: 0xAA poison is negative, never satisfies >=. Ping-pong safety per
// direction: advancing to step p+2 requires observing all own-direction
// sentinels >= p+1, hence every block consumed step p — rows are never
// overwritten while readable. Chain state carried in log2 domain.
__global__ __launch_bounds__(NTHREADS) void fused_kernel(
    const float* __restrict__ means, const float* __restrict__ log_stds,
    const float* __restrict__ eps, float* __restrict__ fbuf,
    float* __restrict__ bbuf, int* __restrict__ fsent, int* __restrict__ bsent,
    float* __restrict__ out)
{
    __shared__ float2 shzD[2][K];    // 32 KB: (z_k, D_k) staging, parity dbuf
    __shared__ float2 lzc[T][CPB];   // own cols: (32*L2E*z, cm2 const)
    __shared__ float smu[T], sstd[T], slq2[T];
    __shared__ float red[NTHREADS];
    __shared__ int ldsflag;

    const int tid  = threadIdx.x;
    const int b    = blockIdx.x;
    const bool fwd = (b < HB);
    const int lb   = fwd ? b : b - HB;   // direction-local block id
    const int col0 = lb * CPB;

    if (tid == 0) ldsflag = 0;

    // ---- setup: thread (t = tid>>4, dcol = tid&15) handles (t, col0+dcol) ----
    {
        int t = tid >> 4, dcol = tid & 15;
        float mu = means[t];
        float st = expf(log_stds[t]);
        if (dcol == 0) {
            smu[t] = mu; sstd[t] = st;
            slq2[t] = L2E_F * (logf(st) + 0.5f * LOG2PI_F);
        }
        float e = eps[t * K + col0 + dcol];
        float z = fmaf(st, e, mu);
        // (z-mu)/st == e exactly: log_q = -0.5 e^2 - ln(st) - 0.5 ln2pi
        float log_q = fmaf(-0.5f * e, e, -logf(st) - 0.5f * LOG2PI_F);
        float tz2 = (32.0f * L2E_F) * z;
        if (fwd) {
            // fwd col const: L2E*(CNORM - log_q) - 16*L2E*z'^2 - log2K
            float cm2 = fmaf((-16.0f * L2E_F) * z, z,
                             L2E_F * (CNORM_F - log_q)) - 11.0f;
            lzc[t][dcol] = make_float2(tz2, cm2);
            if (t == 0) {   // r_0 = -16 z^2 + CNORM - log_q  (log2 domain)
                float r0 = fmaf(-16.0f * z, z, CNORM_F) - log_q;
                astore4(&fbuf[col0 + dcol], r0 * L2E_F);   // parity 0
            }
        } else {
            // bwd row const: -16*L2E*z_j^2 + L2E*CNORM - log2K (no log_q here)
            float cm2 = fmaf((-16.0f * L2E_F) * z, z, L2E_F * CNORM_F) - 11.0f;
            lzc[t][dcol] = make_float2(tz2, cm2);
            if (t == T - 1) {   // c_31 = logN(0.5; z, 1)  (log2 domain)
                float d = 0.5f - z;
                float c31 = fmaf(-0.5f * d, d, -0.5f * LOG2PI_F);
                astore4(&bbuf[col0 + dcol], c31 * L2E_F);  // parity 0
            }
        }
    }
    __syncthreads();               // drains seed stores (vmcnt) + LDS init
    int* mysent = fwd ? fsent : bsent;
    if (tid == 0) sstore(&mysent[lb], 1);

    const int lane = tid & 63;
    const int wave = tid >> 6;     // 0..7: columns 2w, 2w+1
    float* mybuf = fwd ? fbuf : bbuf;
    const int nstep = fwd ? 16 : 15;

    for (int p = 0; p < nstep; ++p) {
        const int par = p & 1;
        const int need = p + 1;
        // inner (staged) time index and own-column time index
        const int tin  = fwd ? p : 31 - p;
        const int town = fwd ? p + 1 : 30 - p;
        const float mu_i  = smu[tin];
        const float std_i = sstd[tin];
        const float lqc   = slq2[tin];      // only used by bwd
        const float* erow = eps + tin * K;

        // ---- pre-poll: z + carried-message addend (r-independent) ----
        float zloc[QS], dadd[QS];
        #pragma unroll
        for (int q = 0; q < QS; ++q) {
            float e = erow[tid + q * NTHREADS];
            float z = fmaf(std_i, e, mu_i);
            zloc[q] = z;
            // fwd: D = r2 - 16*L2E*z^2 ; bwd: D = c2 - L2E*log_q - 16*L2E*z^2
            float base = fwd ? 0.0f : fmaf((0.5f * L2E_F) * e, e, lqc);
            dadd[q] = fmaf((-16.0f * L2E_F) * z, z, base);
        }

        // ---- detection: wave 0 polls own direction's 128 packed sentinels ----
        if (wave == 0) {
            for (;;) {
                int v0 = sload(&mysent[lane]);
                int v1 = sload(&mysent[lane + 64]);
                if (__all(min(v0, v1) >= need)) break;
                __builtin_amdgcn_s_sleep(1);
            }
            __hip_atomic_store(&ldsflag, need, __ATOMIC_RELEASE,
                               __HIP_MEMORY_SCOPE_WORKGROUP);
        } else {
            while (__hip_atomic_load(&ldsflag, __ATOMIC_ACQUIRE,
                                     __HIP_MEMORY_SCOPE_WORKGROUP) < need)
                __builtin_amdgcn_s_sleep(1);
        }

        // ---- one-shot parallel read of the message row + LDS stage ----
        const float* mrow = mybuf + par * K;
        float rv[QS];
        #pragma unroll
        for (int q = 0; q < QS; ++q) rv[q] = aload4(&mrow[tid + q * NTHREADS]);
        #pragma unroll
        for (int q = 0; q < QS; ++q)
            shzD[par][tid + q * NTHREADS] = make_float2(zloc[q], rv[q] + dadd[q]);
        __syncthreads();   // barrier A: stage ready

        // ---- this wave's 2 columns: max pass + exp2 pass over reg'd tiles ----
        const float4* shp = (const float4*)&shzD[par][0];
        float2 zcA = lzc[town][2 * wave];
        float2 zcB = lzc[town][2 * wave + 1];
        float4 fr[16];
        #pragma unroll
        for (int i = 0; i < 16; ++i) fr[i] = shp[lane + (i << 6)];
        float m0 = -INFINITY, m1 = -INFINITY;
        #pragma unroll
        for (int i = 0; i < 16; ++i) {
            m0 = fmaxf(m0, fmaxf(fmaf(zcA.x, fr[i].x, fr[i].y),
                                 fmaf(zcA.x, fr[i].z, fr[i].w)));
            m1 = fmaxf(m1, fmaxf(fmaf(zcB.x, fr[i].x, fr[i].y),
                                 fmaf(zcB.x, fr[i].z, fr[i].w)));
        }
        #pragma unroll
        for (int off = 32; off >= 1; off >>= 1) {
            m0 = fmaxf(m0, __shfl_xor(m0, off, 64));
            m1 = fmaxf(m1, __shfl_xor(m1, off, 64));
        }
        float s0 = 0.0f, s1 = 0.0f;
        #pragma unroll
        for (int i = 0; i < 16; ++i) {
            s0 += EXP2F(fmaf(zcA.x, fr[i].x, fr[i].y) - m0);
            s0 += EXP2F(fmaf(zcA.x, fr[i].z, fr[i].w) - m0);
            s1 += EXP2F(fmaf(zcB.x, fr[i].x, fr[i].y) - m1);
            s1 += EXP2F(fmaf(zcB.x, fr[i].z, fr[i].w) - m1);
        }
        #pragma unroll
        for (int off = 32; off >= 1; off >>= 1) {
            s0 += __shfl_xor(s0, off, 64);
            s1 += __shfl_xor(s1, off, 64);
        }
        if (lane < 2) {
            float mm = lane ? m1 : m0;
            float sv = lane ? s1 : s0;
            float cm = lane ? zcB.y : zcA.y;
            astore4(&mybuf[(par ^ 1) * K + col0 + 2 * wave + lane],
                    cm + mm + LOG2F(sv));
        }
        // barrier B drains every wave's publish (vmcnt) before s_barrier;
        // only then this block's sentinel advances.
        __syncthreads();
        if (tid == 0) sstore(&mysent[lb], p + 2);
    }

    // ---- join: out = lse_j(r_16[j] + c_16[j]) - lnK, block 0 only ----
    if (b == 0) {
        for (;;) {   // one-time poll of BOTH directions (all waves)
            int f0 = sload(&fsent[lane]);
            int f1 = sload(&fsent[lane + 64]);
            int b0 = sload(&bsent[lane]);
            int b1 = sload(&bsent[lane + 64]);
            bool ok = (min(f0, f1) >= 17) && (min(b0, b1) >= 16);
            if (__all(ok)) break;
            __builtin_amdgcn_s_sleep(1);
        }
        const float* rrow = fbuf + 0 * K;   // r_16: parity 16&1 = 0
        const float* crow = bbuf + 1 * K;   // c_16: parity (31-16)&1 = 1
        float vals[QS];
        float m = -INFINITY;
        #pragma unroll
        for (int q = 0; q < QS; ++q) {
            int j = tid + q * NTHREADS;
            float v = aload4(&rrow[j]) + aload4(&crow[j]);   // log2 domain
            vals[q] = v;
            m = fmaxf(m, v);
        }
        red[tid] = m; __syncthreads();
        for (int off = NTHREADS / 2; off >= 1; off >>= 1) {
            if (tid < off) red[tid] = fmaxf(red[tid], red[tid + off]);
            __syncthreads();
        }
        m = red[0]; __syncthreads();
        float ssum = 0.0f;
        #pragma unroll
        for (int q = 0; q < QS; ++q) ssum += EXP2F(vals[q] - m);
        red[tid] = ssum; __syncthreads();
        for (int off = NTHREADS / 2; off >= 1; off >>= 1) {
            if (tid < off) red[tid] += red[tid + off];
            __syncthreads();
        }
        if (tid == 0)
            out[0] = LN2_F * (m + LOG2F(red[0]) - 11.0f);
    }
}

extern "C" void kernel_launch(void* const* d_in, const int* in_sizes, int n_in,
                              void* d_out, int out_size, void* d_ws, size_t ws_size,
                              hipStream_t stream) {
    const float* means    = (const float*)d_in[0];
    const float* log_stds = (const float*)d_in[1];
    const float* eps      = (const float*)d_in[2];
    float* out = (float*)d_out;

    float* fbuf = (float*)d_ws;                 // 2*K fwd ping-pong (16 KB)
    float* bbuf = fbuf + 2 * K;                 // 2*K bwd ping-pong (16 KB)
    int*   fsent = (int*)(bbuf + 2 * K);        // 128 fwd sentinels (512 B)
    int*   bsent = fsent + 128;                 // 128 bwd sentinels (512 B)

    fused_kernel<<<NBLOCKS, NTHREADS, 0, stream>>>(
        means, log_stds, eps, fbuf, bbuf, fsent, bsent, out);
}